// Round 1
// baseline (1185.537 us; speedup 1.0000x reference)
//
#include <hip/hip_runtime.h>
#include <math.h>

#define NN 50000
#define NE 800000
#define TT 6
#define FIN 64
#define HID 48

__device__ __forceinline__ float sigmoidf_(float x){ return 1.0f/(1.0f+__expf(-x)); }

// ---------------- setup kernels ----------------
__global__ __launch_bounds__(256) void k_init(float* deg, int* cnt){
  int i = blockIdx.x*blockDim.x+threadIdx.x;
  if(i<NN){ deg[i]=1.0f; cnt[i]=0; }  // self-loop weight 1 pre-added
}

__global__ __launch_bounds__(256) void k_degcnt(const int* __restrict__ ei, const float* __restrict__ ew,
                                                float* deg, int* cnt){
  int e = blockIdx.x*blockDim.x+threadIdx.x;
  if(e<NE){
    int c = ei[NE+e];
    atomicAdd(&deg[c], ew[e]);
    atomicAdd(&cnt[c], 1);
  }
}

__global__ __launch_bounds__(256) void k_dis(const float* __restrict__ deg, float* dis){
  int i = blockIdx.x*blockDim.x+threadIdx.x;
  if(i<NN){ float d=deg[i]; dis[i] = d>0.f ? rsqrtf(fmaxf(d,1e-12f)) : 0.f; }
}

__global__ __launch_bounds__(1024) void k_scan(const int* __restrict__ cnt, int* offs, int* cursor){
  __shared__ int part[1024];
  int tid=threadIdx.x;
  const int CH=(NN+1023)/1024; // 49
  int lo=tid*CH, hi=lo+CH; if(hi>NN) hi=NN; if(lo>NN) lo=NN;
  int s=0;
  for(int i=lo;i<hi;i++) s+=cnt[i];
  part[tid]=s;
  __syncthreads();
  for(int off=1;off<1024;off<<=1){
    int v = (tid>=off)? part[tid-off] : 0;
    __syncthreads();
    part[tid]+=v;
    __syncthreads();
  }
  int run = (tid==0)?0:part[tid-1];
  for(int i=lo;i<hi;i++){ offs[i]=run; cursor[i]=run; run+=cnt[i]; }
  if(tid==1023) offs[NN]=part[1023];
}

__global__ __launch_bounds__(256) void k_scatter(const int* __restrict__ ei, const float* __restrict__ ew,
                                                 const float* __restrict__ dis, int* cursor,
                                                 int* csr_row, float* csr_nrm){
  int e = blockIdx.x*blockDim.x+threadIdx.x;
  if(e<NE){
    int r=ei[e], c=ei[NE+e];
    int pos=atomicAdd(&cursor[c],1);
    csr_row[pos]=r;
    csr_nrm[pos]=dis[r]*ew[e]*dis[c];
  }
}

__global__ __launch_bounds__(256) void k_transpose(const float* __restrict__ Wih, const float* __restrict__ Whh,
                                                   float* WihT, float* WhhT){
  int i = blockIdx.x*blockDim.x+threadIdx.x; // over 144*48
  if(i<144*HID){
    int o=i/HID, k=i%HID;
    WihT[k*144+o]=Wih[i];
    WhhT[k*144+o]=Whh[i];
  }
}

// ---------------- dense matmul: one thread per node, W via wave-uniform loads ----------------
template<int K>
__global__ __launch_bounds__(256) void k_mm(const float* __restrict__ X, long long in_nstride, long long in_tstride,
                                            const float* __restrict__ Wm, float* __restrict__ out,
                                            long long out_nstride){
  int n = blockIdx.x*blockDim.x+threadIdx.x;
  if(n>=NN) return;
  const float* xr = X + (long long)blockIdx.y*in_tstride + (long long)n*in_nstride;
  float* orow = out + (long long)blockIdx.y*HID + (long long)n*out_nstride;
  float acc[HID];
#pragma unroll
  for(int f=0;f<HID;f++) acc[f]=0.f;
#pragma unroll 2
  for(int k4=0;k4<K/4;k4++){
    float4 xv = *reinterpret_cast<const float4*>(xr + 4*k4);
    const float* wr = Wm + 4*k4*HID;
#pragma unroll
    for(int f=0;f<HID;f++){
      acc[f] = fmaf(xv.x, wr[f],       acc[f]);
      acc[f] = fmaf(xv.y, wr[HID+f],   acc[f]);
      acc[f] = fmaf(xv.z, wr[2*HID+f], acc[f]);
      acc[f] = fmaf(xv.w, wr[3*HID+f], acc[f]);
    }
  }
#pragma unroll
  for(int f4=0;f4<HID/4;f4++){
    *reinterpret_cast<float4*>(orow+4*f4) =
      make_float4(acc[4*f4],acc[4*f4+1],acc[4*f4+2],acc[4*f4+3]);
  }
}

// ---------------- CSR aggregation + bias + LayerNorm + ReLU (+residual), all TC timesteps per edge pass
template<int TC>
__global__ __launch_bounds__(256) void k_agg(const float* __restrict__ Xin, const float* __restrict__ bias,
                                             const float* __restrict__ gain, const float* __restrict__ beta,
                                             const float* __restrict__ resid, float* __restrict__ out,
                                             const int* __restrict__ offs, const int* __restrict__ csr_row,
                                             const float* __restrict__ csr_nrm, const float* __restrict__ dis){
  int wid = (blockIdx.x*blockDim.x+threadIdx.x)>>6;
  int lane = threadIdx.x & 63;
  if(wid>=NN) return;
  const bool act = lane<HID;
  const int f = act? lane : (HID-1);   // clamp so inactive lanes load in-bounds
  float dn = dis[wid];
  float sw = dn*dn;                    // self-loop norm = dis[i]*1*dis[i]
  float acc[TC];
  {
    const float* xs = Xin + (long long)wid*(TC*HID) + f;
#pragma unroll
    for(int t=0;t<TC;t++) acc[t] = sw * xs[t*HID];
  }
  int e0=offs[wid], e1=offs[wid+1];
  int e=e0;
  if(e<e1){
    int r = csr_row[e]; float nr = csr_nrm[e];
    for(++e; e<e1; ++e){
      int r2 = csr_row[e]; float nr2 = csr_nrm[e];   // prefetch next edge
      const float* xr = Xin + (long long)r*(TC*HID) + f;
#pragma unroll
      for(int t=0;t<TC;t++) acc[t] = fmaf(nr, xr[t*HID], acc[t]);
      r=r2; nr=nr2;
    }
    const float* xr = Xin + (long long)r*(TC*HID) + f;
#pragma unroll
    for(int t=0;t<TC;t++) acc[t] = fmaf(nr, xr[t*HID], acc[t]);
  }
  float bb = bias[f], gg = gain[f], be = beta[f];
  const float rn = 1.0f/HID;
#pragma unroll
  for(int t=0;t<TC;t++){
    float val = acc[t] + bb;
    float v = act? val : 0.f;
    float s = v, s2 = v*v;
#pragma unroll
    for(int m=32;m>=1;m>>=1){
      s  += __shfl_xor(s,  m, 64);
      s2 += __shfl_xor(s2, m, 64);
    }
    float mu  = s*rn;
    float var = fmaxf(s2*rn - mu*mu, 0.f);
    float y = (val-mu)*rsqrtf(var+1e-5f)*gg + be;
    y = fmaxf(y, 0.f);
    long long oidx = (long long)wid*(TC*HID) + t*HID + f;
    if(resid) y += resid[oidx];
    if(act) out[oidx] = y;
  }
}

// ---------------- GRU step: 3 threads per node (16 features each), ping-pong hidden ----------------
__global__ __launch_bounds__(256) void k_gru(const float* __restrict__ X, long long xstride,
                                             const float* __restrict__ WihT, const float* __restrict__ WhhT,
                                             const float* __restrict__ bih, const float* __restrict__ bhh,
                                             const float* __restrict__ hin, float* __restrict__ hout){
  int n = blockIdx.x*blockDim.x+threadIdx.x;
  if(n>=NN) return;
  int f0 = blockIdx.y*16;
  const float* xr = X + (long long)n*xstride;
  const float* hr = hin + (long long)n*HID;
  float ra[16], za[16], ia[16], ha[16];
#pragma unroll
  for(int j=0;j<16;j++){ ra[j]=0.f; za[j]=0.f; ia[j]=0.f; ha[j]=0.f; }
  for(int k4=0;k4<HID/4;k4++){
    float4 xv = *reinterpret_cast<const float4*>(xr+4*k4);
    float4 hv = *reinterpret_cast<const float4*>(hr+4*k4);
    const float xs[4]={xv.x,xv.y,xv.z,xv.w};
    const float hs[4]={hv.x,hv.y,hv.z,hv.w};
#pragma unroll
    for(int q=0;q<4;q++){
      const float* wi = WihT + (4*k4+q)*144 + f0;
      const float* wh = WhhT + (4*k4+q)*144 + f0;
#pragma unroll
      for(int j=0;j<16;j++){
        ra[j] = fmaf(xs[q], wi[j],    ra[j]);
        ra[j] = fmaf(hs[q], wh[j],    ra[j]);
        za[j] = fmaf(xs[q], wi[48+j], za[j]);
        za[j] = fmaf(hs[q], wh[48+j], za[j]);
        ia[j] = fmaf(xs[q], wi[96+j], ia[j]);
        ha[j] = fmaf(hs[q], wh[96+j], ha[j]);
      }
    }
  }
#pragma unroll
  for(int j=0;j<16;j++){
    int f=f0+j;
    float r  = sigmoidf_(ra[j]+bih[f]+bhh[f]);
    float ng = tanhf(ia[j]+bih[96+f] + r*(ha[j]+bhh[96+f]));
    float zg = sigmoidf_(za[j]+bih[48+f]+bhh[48+f]);
    float hnew = (1.f-zg)*ng + zg*hr[f];
    hout[(long long)n*HID + f] = hnew;
  }
}

// ---------------- classifier head ----------------
__global__ __launch_bounds__(256) void k_cls(const float* __restrict__ z, const float* __restrict__ Wc1,
                                             const float* __restrict__ bc1, const float* __restrict__ Wc2,
                                             const float* __restrict__ bc2, float* __restrict__ out){
  int n = blockIdx.x*blockDim.x+threadIdx.x;
  if(n>=NN) return;
  const float* zr = z + (long long)n*HID;
  float hv[24];
#pragma unroll
  for(int j=0;j<24;j++) hv[j]=bc1[j];
  for(int k4=0;k4<HID/4;k4++){
    float4 zv = *reinterpret_cast<const float4*>(zr+4*k4);
    const float zs[4]={zv.x,zv.y,zv.z,zv.w};
#pragma unroll
    for(int q=0;q<4;q++){
      const float* wr = Wc1 + (4*k4+q)*24;
#pragma unroll
      for(int j=0;j<24;j++) hv[j] = fmaf(zs[q], wr[j], hv[j]);
    }
  }
  float l0=bc2[0], l1=bc2[1];
#pragma unroll
  for(int j=0;j<24;j++){
    float a = fmaxf(hv[j],0.f);
    l0 = fmaf(a, Wc2[2*j],   l0);
    l1 = fmaf(a, Wc2[2*j+1], l1);
  }
  out[2LL*n]=l0; out[2LL*n+1]=l1;
}

static inline size_t al256(size_t x){ return (x+255)&~(size_t)255; }

extern "C" void kernel_launch(void* const* d_in, const int* in_sizes, int n_in,
                              void* d_out, int out_size, void* d_ws, size_t ws_size,
                              hipStream_t stream){
  const float* x_seq=(const float*)d_in[0];
  const int*   ei   =(const int*)d_in[1];
  const float* ew   =(const float*)d_in[2];
  const float* W0=(const float*)d_in[3];  const float* b0=(const float*)d_in[4];
  const float* g0=(const float*)d_in[5];  const float* be0=(const float*)d_in[6];
  const float* W1=(const float*)d_in[7];  const float* b1=(const float*)d_in[8];
  const float* g1=(const float*)d_in[9];  const float* be1=(const float*)d_in[10];
  const float* Wih=(const float*)d_in[11];const float* Whh=(const float*)d_in[12];
  const float* bih=(const float*)d_in[13];const float* bhh=(const float*)d_in[14];
  const float* Wc1=(const float*)d_in[15];const float* bc1=(const float*)d_in[16];
  const float* Wc2=(const float*)d_in[17];const float* bc2=(const float*)d_in[18];
  float* outp=(float*)d_out;

  char* p=(char*)d_ws; size_t off=0;
  auto alloc=[&](size_t bytes)->void*{ void* r=p+off; off=al256(off+bytes); return r; };
  float* deg    =(float*)alloc((size_t)NN*4);
  float* dis    =(float*)alloc((size_t)NN*4);
  int*   cnt    =(int*)  alloc((size_t)NN*4);
  int*   offs   =(int*)  alloc((size_t)(NN+1)*4);
  int*   cursor =(int*)  alloc((size_t)NN*4);
  int*   csr_row=(int*)  alloc((size_t)NE*4);
  float* csr_nrm=(float*)alloc((size_t)NE*4);
  float* WihT   =(float*)alloc((size_t)144*48*4);
  float* WhhT   =(float*)alloc((size_t)144*48*4);
  float* z0     =(float*)alloc((size_t)NN*HID*4);
  float* z1     =(float*)alloc((size_t)NN*HID*4);
  size_t base=off;
  size_t bufsz6=al256((size_t)NN*TT*HID*4);
  size_t bufsz1=al256((size_t)NN*HID*4);
  bool batched = (base + 3*bufsz6) <= ws_size;

  const int GN=(NN+255)/256, GE=(NE+255)/256, GW=(NN*64+255)/256;

  k_init   <<<GN,256,0,stream>>>(deg,cnt);
  k_degcnt <<<GE,256,0,stream>>>(ei,ew,deg,cnt);
  k_dis    <<<GN,256,0,stream>>>(deg,dis);
  k_scan   <<<1,1024,0,stream>>>(cnt,offs,cursor);
  k_scatter<<<GE,256,0,stream>>>(ei,ew,dis,cursor,csr_row,csr_nrm);
  k_transpose<<<(144*48+255)/256,256,0,stream>>>(Wih,Whh,WihT,WhhT);
  hipMemsetAsync(z0,0,(size_t)NN*HID*4,stream);

  if(batched){
    float* A=(float*)(p+base);
    float* B=(float*)(p+base+bufsz6);
    float* C=(float*)(p+base+2*bufsz6);
    // layer 0 (all 6 t)
    k_mm<64><<<dim3(GN,TT),256,0,stream>>>(x_seq, 64, (long long)NN*64, W0, A, (long long)TT*HID);
    k_agg<TT><<<GW,256,0,stream>>>(A,b0,g0,be0,nullptr,B,offs,csr_row,csr_nrm,dis);
    // layer 1 (all 6 t), residual = B
    k_mm<48><<<dim3(GN,TT),256,0,stream>>>(B, (long long)TT*HID, HID, W1, A, (long long)TT*HID);
    k_agg<TT><<<GW,256,0,stream>>>(A,b1,g1,be1,B,C,offs,csr_row,csr_nrm,dis);
    // GRU over time
    for(int t=0;t<TT;t++){
      const float* hin=(t&1)? z1:z0;
      float* hout=(t&1)? z0:z1;
      k_gru<<<dim3(GN,3),256,0,stream>>>(C+(long long)t*HID, (long long)TT*HID, WihT,WhhT,bih,bhh,hin,hout);
    }
  } else {
    float* A=(float*)(p+base);
    float* B=(float*)(p+base+bufsz1);
    float* C=(float*)(p+base+2*bufsz1);
    for(int t=0;t<TT;t++){
      k_mm<64><<<dim3(GN,1),256,0,stream>>>(x_seq+(size_t)t*NN*64, 64, 0, W0, A, HID);
      k_agg<1><<<GW,256,0,stream>>>(A,b0,g0,be0,nullptr,B,offs,csr_row,csr_nrm,dis);
      k_mm<48><<<dim3(GN,1),256,0,stream>>>(B, HID, 0, W1, A, HID);
      k_agg<1><<<GW,256,0,stream>>>(A,b1,g1,be1,B,C,offs,csr_row,csr_nrm,dis);
      const float* hin=(t&1)? z1:z0;
      float* hout=(t&1)? z0:z1;
      k_gru<<<dim3(GN,3),256,0,stream>>>(C, HID, WihT,WhhT,bih,bhh,hin,hout);
    }
  }
  // after t=5 (odd), final hidden is in z0
  k_cls<<<GN,256,0,stream>>>(z0,Wc1,bc1,Wc2,bc2,outp);
}